// Round 9
// baseline (255.271 us; speedup 1.0000x reference)
//
#include <hip/hip_runtime.h>
#include <hip/hip_bf16.h>

// Problem constants (from setup_inputs): bs=16, nq=64, ngt=32, D=4096, ncls=33
#define BS   16
#define NQ   64
#define NGT  32
#define DIM  4096
#define NCLS 33

#define QT      8               // heat rows per block
#define NCHUNK  8               // D split
#define CHUNK   (DIM / NCHUNK)  // 512

#define SOLVE_REPS 8            // MEASUREMENT: inflate lsap to read its dur off top-5

// ---------------------------------------------------------------------------
// Kernel 1: partial cost  Cp[b][q][g][c] = sum_{d in chunk c} |heat[b,q,d]-gt[b,g,d]|
// (byte-identical to round 5/8)
// ---------------------------------------------------------------------------
__global__ __launch_bounds__(256) void cost_kernel(
    const float* __restrict__ heat, const float* __restrict__ gt,
    float* __restrict__ Cp)
{
    __shared__ float hrow[QT][CHUNK];   // 16 KB
    const int bid  = blockIdx.x;        // 16*8*8 = 1024 blocks
    const int b    = bid & 15;
    const int rest = bid >> 4;          // 0..63
    const int qt   = rest & (NQ / QT - 1);  // 0..7
    const int c    = rest >> 3;         // 0..7
    const int q0   = qt * QT;

    const float* hbase = heat + ((size_t)(b * NQ + q0)) * DIM + c * CHUNK;
    for (int i = threadIdx.x; i < QT * CHUNK / 4; i += 256) {
        int r = i >> 7;        // / (CHUNK/4 = 128)
        int k = i & 127;
        ((float4*)hrow[r])[k] = ((const float4*)(hbase + (size_t)r * DIM))[k];
    }
    __syncthreads();

    const int wave = threadIdx.x >> 6;
    const int lane = threadIdx.x & 63;
    const int g0 = wave * 8;
    const float* gbase = gt + ((size_t)(b * NGT + g0)) * DIM + c * CHUNK;

    float acc[8][QT];
    #pragma unroll
    for (int g = 0; g < 8; ++g)
        #pragma unroll
        for (int q = 0; q < QT; ++q) acc[g][q] = 0.f;

    for (int i = lane; i < CHUNK / 4; i += 64) {   // 2 iterations
        float4 hv[QT];
        #pragma unroll
        for (int q = 0; q < QT; ++q) hv[q] = ((float4*)hrow[q])[i];
        #pragma unroll
        for (int g = 0; g < 8; ++g) {
            float4 gv = ((const float4*)(gbase + (size_t)g * DIM))[i];
            #pragma unroll
            for (int q = 0; q < QT; ++q) {
                acc[g][q] += fabsf(hv[q].x - gv.x) + fabsf(hv[q].y - gv.y) +
                             fabsf(hv[q].z - gv.z) + fabsf(hv[q].w - gv.w);
            }
        }
    }

    // 64-value butterfly: after 6 stages lane l holds total of value index l
    float r[64];
    #pragma unroll
    for (int k = 0; k < 64; ++k) r[k] = acc[k >> 3][k & 7];
    #pragma unroll
    for (int n = 64, m = 1; n > 1; n >>= 1, m <<= 1) {
        #pragma unroll
        for (int k = 0; k < 32; ++k) {
            if (k < n / 2) {
                float a  = r[2 * k], bb = r[2 * k + 1];
                bool  hi = (lane & m) != 0;
                float keep = hi ? bb : a;
                float send = hi ? a : bb;
                r[k] = keep + __shfl_xor(send, m);
            }
        }
    }
    {
        int gl = lane >> 3, ql = lane & 7;
        Cp[(((size_t)(b * NQ + (q0 + ql))) * NGT + (g0 + gl)) * NCHUNK + c] = r[0];
    }
}

// ---------------------------------------------------------------------------
// Helpers.
// ---------------------------------------------------------------------------
template<int CTRL>
__device__ __forceinline__ float dppmin_t(float x) {
    int t = __builtin_amdgcn_update_dpp(__float_as_int(x), __float_as_int(x),
                                        CTRL, 0xf, 0xf, false);
    return fminf(x, __int_as_float(t));
}
__device__ __forceinline__ float rdlane_f(float x, int l) {
    return __int_as_float(__builtin_amdgcn_readlane(__float_as_int(x), l));
}
// Exact min over all 64 lanes, wave-uniform result.
__device__ __forceinline__ float wavemin64(float x) {
    x = dppmin_t<0xB1>(x);    // quad_perm xor1
    x = dppmin_t<0x4E>(x);    // quad_perm xor2
    x = dppmin_t<0x141>(x);   // row_half_mirror -> min over 8
    x = dppmin_t<0x140>(x);   // row_mirror      -> min over 16
    x = dppmin_t<0x142>(x);   // row_bcast15
    x = dppmin_t<0x143>(x);   // row_bcast31 -> lane63 = min over 64
    return rdlane_f(x, 63);
}

// Uniform-index select from 32 register-resident floats, forced onto the VALU:
// copy the (uniform) index into a VGPR via asm so the compiler emits a
// v_cmp + v_cndmask binary tree (31 cndmasks, ~80 cy issue) instead of a
// scalar jump table (round-6 failure) or a ds_read (~120 cy latency).
__device__ __forceinline__ float sel32_valu(const float* __restrict__ c, int i_s) {
    int vi;
    asm("v_mov_b32 %0, %1" : "=v"(vi) : "s"(i_s));
    const bool b0 = (vi & 1), b1 = (vi & 2), b2 = (vi & 4), b3 = (vi & 8), b4 = (vi & 16);
    float t0[16], t1[8], t2[4], t3[2];
    #pragma unroll
    for (int k = 0; k < 16; ++k) t0[k] = b0 ? c[2 * k + 1] : c[2 * k];
    #pragma unroll
    for (int k = 0; k < 8; ++k)  t1[k] = b1 ? t0[2 * k + 1] : t0[2 * k];
    #pragma unroll
    for (int k = 0; k < 4; ++k)  t2[k] = b2 ? t1[2 * k + 1] : t1[2 * k];
    #pragma unroll
    for (int k = 0; k < 2; ++k)  t3[k] = b3 ? t2[2 * k + 1] : t2[2 * k];
    return b4 ? t3[1] : t3[0];
}

// ---------------------------------------------------------------------------
// Kernel 2: exact rectangular LSAP (Jonker-Volgenant + greedy dual init),
// one block per batch; wave 0 solves with a register-resident cost column.
// MEASUREMENT BUILD: the {init+solve} is repeated SOLVE_REPS times (state
// fully reset each rep; keep-alive asm prevents DCE of reps 0..N-2) so the
// dispatch's dur_us on rocprof isolates the solver cost: S = (dur-2)/8 - 1.5.
// ---------------------------------------------------------------------------
__global__ __launch_bounds__(256) void lsap_kernel(
    const float* __restrict__ Cp, const float* __restrict__ prob,
    const int* __restrict__ label, int* __restrict__ out)
{
    __shared__ float cost[NGT * NQ];
    const int b = blockIdx.x;
    const int tid = threadIdx.x;

    for (int idx = tid; idx < NQ * NGT; idx += 256) {
        int q = idx & 63;
        int g = idx >> 6;
        const float* p = &Cp[(((size_t)(b * NQ + q)) * NGT + g) * NCHUNK];
        float4 v4a = *(const float4*)p;
        float4 v4b = *(const float4*)(p + 4);
        int lb = label[b * NGT + g];
        float cpr = 1.0f - prob[((size_t)(b * NQ + q)) * NCLS + lb];
        float s = ((v4a.x + v4a.y) + (v4a.z + v4a.w)) +
                  ((v4b.x + v4b.y) + (v4b.z + v4b.w));
        cost[g * 64 + q] = s + cpr;
    }
    __syncthreads();
    if (tid >= 64) return;            // wave 0 solves alone
    const int lane = tid;

    // This lane's column of the cost matrix, in registers (once).
    float creg[NGT];
    #pragma unroll
    for (int g = 0; g < NGT; ++g) creg[g] = cost[(g << 6) + lane];

    const float INF = __builtin_inff();
    float v = 0.f, u_reg = 0.f;
    int c4r = -1, r4c = -1;

    #pragma clang loop unroll(disable)
    for (int rep = 0; rep < SOLVE_REPS; ++rep) {
        v = 0.f; u_reg = 0.f; c4r = -1; r4c = -1;   // full state reset per rep

        // ---- greedy init: u[g] = min_q cost[g][q]; match first-argmin if free ----
        {
            float mg[NGT]; int jg[NGT];
            #pragma unroll
            for (int g = 0; g < NGT; ++g) {
                float m = wavemin64(creg[g]);
                unsigned long long ball = __ballot(creg[g] == m);
                jg[g] = __ffsll(ball) - 1;
                mg[g] = m;
            }
            #pragma unroll
            for (int g = 0; g < NGT; ++g) {
                int j = jg[g];
                int rtaken = __builtin_amdgcn_readlane(r4c, j);
                if (rtaken < 0) {
                    if (lane == j) r4c = g;
                    if (lane == g) c4r = j;
                }
                if (lane == g) u_reg = mg[g];
            }
        }

        for (int cur = 0; cur < NGT; ++cur) {
            if (__builtin_amdgcn_readlane(c4r, cur) >= 0) continue;

            unsigned SRmask = 0;
            float shortest = INF;
            int pathv = 0;
            bool SC = false;
            float minVal = 0.f;
            int i = cur;
            int sink = -1;

            while (sink < 0) {
                SRmask |= (1u << i);
                float ci = sel32_valu(creg, i);     // register select, no LDS
                float ui = rdlane_f(u_reg, i);
                float lowest = minVal + ci - ui - v;
                if (!SC && lowest < shortest) { shortest = lowest; pathv = i; }
                float masked = SC ? INF : shortest;
                float mv = wavemin64(masked);
                unsigned long long ball = __ballot(masked == mv);
                int j = __ffsll(ball) - 1;          // first-index tie-break
                minVal = mv;
                if (lane == j) SC = true;
                int rr = __builtin_amdgcn_readlane(r4c, j);
                if (rr < 0) sink = j;
                else        i = rr;
            }

            // ---- dual updates (pre-augment col4row) ----
            if (lane == cur) u_reg += minVal;
            {
                float shc = __shfl(shortest, c4r & 63);
                bool rowupd = (lane < NGT) && (lane != cur) && ((SRmask >> lane) & 1u);
                if (rowupd) u_reg += minVal - shc;
            }
            if (SC) v -= minVal - shortest;

            // ---- augment back from sink ----
            int j = sink;
            while (true) {
                int ii = __builtin_amdgcn_readlane(pathv, j);
                if (lane == j) r4c = ii;
                int prev = __builtin_amdgcn_readlane(c4r, ii);
                if (lane == ii) c4r = j;
                if (ii == cur) break;
                j = prev;
            }
        }

        // keep every rep's results observable so reps 0..N-2 aren't DCE'd
        asm volatile("" :: "v"(c4r), "v"(r4c), "v"(u_reg), "v"(v));
    }

    // ---- argsort(col4row) and write (rows, cols) ----
    int cc = c4r;
    int rank = 0;
    for (int t = 0; t < NGT; ++t) {
        int ct = __shfl(c4r, t);
        rank += (ct < cc) ? 1 : 0;
    }
    if (lane < NGT) {
        out[b * NGT + rank] = cc;                   // rows: matched query idx
        out[BS * NGT + b * NGT + rank] = lane;      // cols: corresponding gt idx
    }
}

extern "C" void kernel_launch(void* const* d_in, const int* in_sizes, int n_in,
                              void* d_out, int out_size, void* d_ws, size_t ws_size,
                              hipStream_t stream) {
    const float* prob  = (const float*)d_in[0];
    const int*   label = (const int*)d_in[1];
    const float* heat  = (const float*)d_in[2];
    const float* gt    = (const float*)d_in[3];
    int* out = (int*)d_out;
    float* Cp = (float*)d_ws;   // BS*NQ*NGT*NCHUNK floats = 1 MiB

    cost_kernel<<<dim3(BS * (NQ / QT) * NCHUNK), dim3(256), 0, stream>>>(heat, gt, Cp);
    lsap_kernel<<<dim3(BS), dim3(256), 0, stream>>>(Cp, prob, label, out);
}

// Round 10
// 33.832 us; speedup vs baseline: 7.5453x; 7.5453x over previous
//
#include <hip/hip_runtime.h>
#include <hip/hip_bf16.h>

// Problem constants (from setup_inputs): bs=16, nq=64, ngt=32, D=4096, ncls=33
#define BS   16
#define NQ   64
#define NGT  32
#define DIM  4096
#define NCLS 33

#define QT      4               // heat rows per block (halved: 2048 blocks -> ~8/CU)
#define NCHUNK  8               // D split (layout unchanged for lsap)
#define CHUNK   (DIM / NCHUNK)  // 512

// ---------------------------------------------------------------------------
// Kernel 1: partial cost  Cp[b][q][g][c] = sum_{d in chunk c} |heat[b,q,d]-gt[b,g,d]|
// Block = (b, q-tile of 4, chunk): 16*16*8 = 2048 blocks (~8/CU -> latency
// hiding doubled vs round 8's 1024). b = bid&15 pins batches to XCDs.
// 4 waves x (8 gt x 4 q) register tile; 8 KB LDS heat staging.
// ---------------------------------------------------------------------------
__global__ __launch_bounds__(256) void cost_kernel(
    const float* __restrict__ heat, const float* __restrict__ gt,
    float* __restrict__ Cp)
{
    __shared__ float hrow[QT][CHUNK];   // 8 KB
    const int bid  = blockIdx.x;        // 2048 blocks
    const int b    = bid & 15;
    const int rest = bid >> 4;          // 0..127
    const int qt   = rest & (NQ / QT - 1);  // 0..15
    const int c    = rest >> 4;         // 0..7
    const int q0   = qt * QT;

    // stage 4 heat rows (chunk c): 512 float4s, 2 per thread
    const float* hbase = heat + ((size_t)(b * NQ + q0)) * DIM + c * CHUNK;
    #pragma unroll
    for (int i = threadIdx.x; i < QT * CHUNK / 4; i += 256) {
        int r = i >> 7;        // / (CHUNK/4 = 128)
        int k = i & 127;
        ((float4*)hrow[r])[k] = ((const float4*)(hbase + (size_t)r * DIM))[k];
    }
    __syncthreads();

    const int wave = threadIdx.x >> 6;
    const int lane = threadIdx.x & 63;
    const int g0 = wave * 8;
    const float* gbase = gt + ((size_t)(b * NGT + g0)) * DIM + c * CHUNK;

    float acc[8][QT];
    #pragma unroll
    for (int g = 0; g < 8; ++g)
        #pragma unroll
        for (int q = 0; q < QT; ++q) acc[g][q] = 0.f;

    #pragma unroll
    for (int i0 = 0; i0 < CHUNK / 4; i0 += 64) {   // 2 iterations
        const int i = i0 + lane;
        float4 hv[QT];
        #pragma unroll
        for (int q = 0; q < QT; ++q) hv[q] = ((float4*)hrow[q])[i];
        #pragma unroll
        for (int g = 0; g < 8; ++g) {
            float4 gv = ((const float4*)(gbase + (size_t)g * DIM))[i];
            #pragma unroll
            for (int q = 0; q < QT; ++q) {
                acc[g][q] += fabsf(hv[q].x - gv.x) + fabsf(hv[q].y - gv.y) +
                             fabsf(hv[q].z - gv.z) + fabsf(hv[q].w - gv.w);
            }
        }
    }

    // 32-value butterfly across 64 lanes; lane l (l<32) ends with value l
    // (value index k = g*4 + q).
    float r[32];
    #pragma unroll
    for (int k = 0; k < 32; ++k) r[k] = acc[k >> 2][k & 3];
    #pragma unroll
    for (int n = 32, m = 1; n > 1; n >>= 1, m <<= 1) {
        #pragma unroll
        for (int k = 0; k < 32; ++k) {
            if (k < n / 2) {
                float a  = r[2 * k], bb = r[2 * k + 1];
                bool  hi = (lane & m) != 0;
                float keep = hi ? bb : a;
                float send = hi ? a : bb;
                r[k] = keep + __shfl_xor(send, m);
            }
        }
    }
    float tot = r[0] + __shfl_xor(r[0], 32);
    if (lane < 32) {
        int gl = lane >> 2, ql = lane & 3;
        Cp[(((size_t)(b * NQ + (q0 + ql))) * NGT + (g0 + gl)) * NCHUNK + c] = tot;
    }
}

// ---------------------------------------------------------------------------
// Helpers.
// ---------------------------------------------------------------------------
template<int CTRL>
__device__ __forceinline__ float dppmin_t(float x) {
    int t = __builtin_amdgcn_update_dpp(__float_as_int(x), __float_as_int(x),
                                        CTRL, 0xf, 0xf, false);
    return fminf(x, __int_as_float(t));
}
__device__ __forceinline__ float rdlane_f(float x, int l) {
    return __int_as_float(__builtin_amdgcn_readlane(__float_as_int(x), l));
}
// Exact min over all 64 lanes, wave-uniform result.
__device__ __forceinline__ float wavemin64(float x) {
    x = dppmin_t<0xB1>(x);    // quad_perm xor1
    x = dppmin_t<0x4E>(x);    // quad_perm xor2
    x = dppmin_t<0x141>(x);   // row_half_mirror -> min over 8
    x = dppmin_t<0x140>(x);   // row_mirror      -> min over 16
    x = dppmin_t<0x142>(x);   // row_bcast15
    x = dppmin_t<0x143>(x);   // row_bcast31 -> lane63 = min over 64
    return rdlane_f(x, 63);
}

// ---------------------------------------------------------------------------
// Kernel 2: exact rectangular LSAP (Jonker-Volgenant + greedy dual init),
// one block per batch; round-8 solver (LDS-resident cost matrix — round 9
// proved the register-resident variant spills and is 2x slower). Greedy init
// processes rows in groups of 8 (24 live regs, no spill): u[g]=min_q cost,
// match first-argmin if free. Dijkstra only for remaining rows. Output =
// unique optimum = reference (first-index tie-breaks preserved).
// ---------------------------------------------------------------------------
__global__ __launch_bounds__(256, 1) void lsap_kernel(
    const float* __restrict__ Cp, const float* __restrict__ prob,
    const int* __restrict__ label, int* __restrict__ out)
{
    __shared__ float cost[NGT * NQ];
    const int b = blockIdx.x;
    const int tid = threadIdx.x;

    for (int idx = tid; idx < NQ * NGT; idx += 256) {
        int q = idx & 63;
        int g = idx >> 6;
        const float* p = &Cp[(((size_t)(b * NQ + q)) * NGT + g) * NCHUNK];
        float4 v4a = *(const float4*)p;
        float4 v4b = *(const float4*)(p + 4);
        int lb = label[b * NGT + g];
        float cpr = 1.0f - prob[((size_t)(b * NQ + q)) * NCLS + lb];
        float s = ((v4a.x + v4a.y) + (v4a.z + v4a.w)) +
                  ((v4b.x + v4b.y) + (v4b.z + v4b.w));
        cost[g * 64 + q] = s + cpr;
    }
    __syncthreads();
    if (tid >= 64) return;            // wave 0 solves alone
    const int lane = tid;

    const float INF = __builtin_inff();
    float v = 0.f;        // dual for column `lane`
    float u_reg = 0.f;    // dual for row `lane` (valid lane<32)
    int c4r = -1;         // col4row for row `lane` (valid lane<32)
    int r4c = -1;         // row4col for column `lane`

    // ---- greedy init, groups of 8 (pipelined ds_reads, small reg footprint) ----
    #pragma unroll
    for (int gb = 0; gb < NGT; gb += 8) {
        float xs[8]; float ms[8]; int js[8];
        #pragma unroll
        for (int t = 0; t < 8; ++t) xs[t] = cost[((gb + t) << 6) + lane];
        #pragma unroll
        for (int t = 0; t < 8; ++t) {
            ms[t] = wavemin64(xs[t]);
            unsigned long long ball = __ballot(xs[t] == ms[t]);
            js[t] = __ffsll(ball) - 1;
        }
        #pragma unroll
        for (int t = 0; t < 8; ++t) {
            int g = gb + t, j = js[t];
            int rtaken = __builtin_amdgcn_readlane(r4c, j);
            if (rtaken < 0) {
                if (lane == j) r4c = g;
                if (lane == g) c4r = j;
            }
            if (lane == g) u_reg = ms[t];
        }
    }

    for (int cur = 0; cur < NGT; ++cur) {
        if (__builtin_amdgcn_readlane(c4r, cur) >= 0) continue;  // greedy-matched

        unsigned SRmask = 0;
        float shortest = INF;
        int pathv = 0;
        bool SC = false;
        float minVal = 0.f;
        int i = cur;
        int sink = -1;

        while (sink < 0) {
            SRmask |= (1u << i);
            float ci = cost[(i << 6) + lane];
            float ui = rdlane_f(u_reg, i);
            float lowest = minVal + ci - ui - v;
            if (!SC && lowest < shortest) { shortest = lowest; pathv = i; }
            float masked = SC ? INF : shortest;
            float mv = wavemin64(masked);
            unsigned long long ball = __ballot(masked == mv);
            int j = __ffsll(ball) - 1;          // first-index tie-break
            minVal = mv;
            if (lane == j) SC = true;
            int rr = __builtin_amdgcn_readlane(r4c, j);
            if (rr < 0) sink = j;
            else        i = rr;
        }

        // ---- dual updates (pre-augment col4row) ----
        if (lane == cur) u_reg += minVal;
        {
            float shc = __shfl(shortest, c4r & 63);
            bool rowupd = (lane < NGT) && (lane != cur) && ((SRmask >> lane) & 1u);
            if (rowupd) u_reg += minVal - shc;
        }
        if (SC) v -= minVal - shortest;

        // ---- augment back from sink ----
        int j = sink;
        while (true) {
            int ii = __builtin_amdgcn_readlane(pathv, j);
            if (lane == j) r4c = ii;
            int prev = __builtin_amdgcn_readlane(c4r, ii);
            if (lane == ii) c4r = j;
            if (ii == cur) break;
            j = prev;
        }
    }

    // ---- argsort(col4row) and write (rows, cols) ----
    int cc = c4r;
    int rank = 0;
    for (int t = 0; t < NGT; ++t) {
        int ct = __shfl(c4r, t);
        rank += (ct < cc) ? 1 : 0;
    }
    if (lane < NGT) {
        out[b * NGT + rank] = cc;                   // rows: matched query idx
        out[BS * NGT + b * NGT + rank] = lane;      // cols: corresponding gt idx
    }
}

extern "C" void kernel_launch(void* const* d_in, const int* in_sizes, int n_in,
                              void* d_out, int out_size, void* d_ws, size_t ws_size,
                              hipStream_t stream) {
    const float* prob  = (const float*)d_in[0];
    const int*   label = (const int*)d_in[1];
    const float* heat  = (const float*)d_in[2];
    const float* gt    = (const float*)d_in[3];
    int* out = (int*)d_out;
    float* Cp = (float*)d_ws;   // BS*NQ*NGT*NCHUNK floats = 1 MiB

    cost_kernel<<<dim3(BS * (NQ / QT) * NCHUNK), dim3(256), 0, stream>>>(heat, gt, Cp);
    lsap_kernel<<<dim3(BS), dim3(256), 0, stream>>>(Cp, prob, label, out);
}